// Round 1
// baseline (319.228 us; speedup 1.0000x reference)
//
#include <hip/hip_runtime.h>
#include <hip/hip_bf16.h>
#include <math.h>

// Problem constants: B=2, T=2048, C=1024, H=16, D=64
#define T_SEQ 2048
#define NHEAD 16
#define HDIM  64
#define CDIM  1024
#define KDIM  1024
#define ATT_SCALE 0.125f

typedef __attribute__((ext_vector_type(8))) short bf16x8;
typedef __attribute__((ext_vector_type(4))) float f32x4;
typedef __attribute__((ext_vector_type(8))) unsigned short u16x8;

__device__ __forceinline__ unsigned short f2bf(float f) {
    unsigned int u = __builtin_bit_cast(unsigned int, f);
    u += 0x7fffu + ((u >> 16) & 1u);   // round-to-nearest-even
    return (unsigned short)(u >> 16);
}

// ---------------------------------------------------------------------------
// GEMM: C[4096, NC] = A[4096,1024] @ W[1024, NC] + bias
//  EPI 0: route outputs to Q[B,H,T,D], K[B,H,T,D], V^T[B,H,D,T] as bf16 (NC=3072)
//  EPI 1: plain fp32 store to Of[4096, NC] (NC=1024)
// Tile 128x128, 4 waves (2x2 of 64x64), BK=32, mfma_f32_16x16x32_bf16.
// ---------------------------------------------------------------------------
template<int NC, bool ABF16, int EPI>
__global__ __launch_bounds__(256) void gemm_k(
    const void* __restrict__ Ap, const float* __restrict__ W,
    const float* __restrict__ bias, float* __restrict__ Of,
    unsigned short* __restrict__ Qb, unsigned short* __restrict__ Kb,
    unsigned short* __restrict__ Vt)
{
    __shared__ unsigned short As[128][40];  // 40-elem (80B) row stride: 2-way bank alias = free
    __shared__ unsigned short Bs[128][40];  // Bs[n][k] (W tile transposed)

    const int tid  = threadIdx.x;
    const int lane = tid & 63;
    const int wid  = tid >> 6;
    const int m0 = blockIdx.x * 128;
    const int n0 = blockIdx.y * 128;
    const int wm = (wid >> 1) * 64;
    const int wn = (wid & 1) * 64;
    const int rl = lane & 15;
    const int kq = (lane >> 4) * 8;

    f32x4 acc[4][4] = {};

    for (int k0 = 0; k0 < KDIM; k0 += 32) {
        // ---- stage A tile [128][32] -> bf16 LDS ----
        if (!ABF16) {
            const float* Af = (const float*)Ap;
            #pragma unroll
            for (int i = 0; i < 4; i++) {
                int lin = i * 256 + tid;       // 0..1023
                int row = lin >> 3;            // 8 float4 per row
                int c4  = (lin & 7) * 4;
                float4 v = *(const float4*)(Af + (size_t)(m0 + row) * KDIM + k0 + c4);
                ushort4 h;
                h.x = f2bf(v.x); h.y = f2bf(v.y); h.z = f2bf(v.z); h.w = f2bf(v.w);
                *(ushort4*)&As[row][c4] = h;
            }
        } else {
            const unsigned short* Ah = (const unsigned short*)Ap;
            #pragma unroll
            for (int i = 0; i < 2; i++) {
                int lin = i * 256 + tid;       // 0..511
                int row = lin >> 2;            // 4 chunks of 8 bf16 per row
                int c8  = (lin & 3) * 8;
                u16x8 v = *(const u16x8*)(Ah + (size_t)(m0 + row) * KDIM + k0 + c8);
                *(u16x8*)&As[row][c8] = v;
            }
        }
        // ---- stage W tile [32][128] transposed -> Bs[n][k] ----
        // k-strided global reads, coalesced across n (each j: 128 consecutive addrs)
        {
            int n  = tid & 127;
            int kc = (tid >> 7) * 16;          // 0 or 16
            u16x8 t0, t1;
            #pragma unroll
            for (int j = 0; j < 8; j++)
                t0[j] = (short)f2bf(W[(size_t)(k0 + kc + j) * NC + n0 + n]);
            #pragma unroll
            for (int j = 0; j < 8; j++)
                t1[j] = (short)f2bf(W[(size_t)(k0 + kc + 8 + j) * NC + n0 + n]);
            *(u16x8*)&Bs[n][kc]     = t0;
            *(u16x8*)&Bs[n][kc + 8] = t1;
        }
        __syncthreads();

        bf16x8 af[4], bfr[4];
        #pragma unroll
        for (int f = 0; f < 4; f++) {
            af[f]  = *(const bf16x8*)&As[wm + f*16 + rl][kq];
            bfr[f] = *(const bf16x8*)&Bs[wn + f*16 + rl][kq];
        }
        #pragma unroll
        for (int i = 0; i < 4; i++)
            #pragma unroll
            for (int j = 0; j < 4; j++)
                acc[i][j] = __builtin_amdgcn_mfma_f32_16x16x32_bf16(af[i], bfr[j], acc[i][j], 0, 0, 0);
        __syncthreads();
    }

    // ---- epilogue ----
    #pragma unroll
    for (int j = 0; j < 4; j++) {
        int gn = n0 + wn + j*16 + rl;
        float bv = bias[gn];
        #pragma unroll
        for (int i = 0; i < 4; i++) {
            int gm0 = m0 + wm + i*16 + (lane >> 4) * 4;
            #pragma unroll
            for (int r = 0; r < 4; r++) {
                float v = acc[i][j][r] + bv;
                int gm = gm0 + r;
                if (EPI == 0) {
                    int which = gn >> 10;          // 0=q 1=k 2=v
                    int cw = gn & 1023;
                    int h = cw >> 6, d = cw & 63;
                    int b = gm >> 11, t = gm & 2047;
                    size_t bh = (size_t)(b * NHEAD + h);
                    unsigned short hv = f2bf(v);
                    if (which == 0)      Qb[(bh * T_SEQ + t) * HDIM + d] = hv;
                    else if (which == 1) Kb[(bh * T_SEQ + t) * HDIM + d] = hv;
                    else                 Vt[(bh * HDIM + d) * T_SEQ + t] = hv;
                } else {
                    Of[(size_t)gm * NC + gn] = v;
                }
            }
        }
    }
}

// ---------------------------------------------------------------------------
// Causal flash attention. Block = 4 waves; each wave owns 16 q-rows
// independently, loops KV tiles of 32. QK^T and PV via 16x16x32 bf16 MFMA;
// P round-trips through per-wave LDS. Online softmax, row stats in 16-lane
// shuffle groups (row = (lane>>4)*4+reg, col = lane&15 of each 16x16 frag).
// ---------------------------------------------------------------------------
__global__ __launch_bounds__(256) void attn_k(
    const unsigned short* __restrict__ Qb, const unsigned short* __restrict__ Kb,
    const unsigned short* __restrict__ Vt, unsigned short* __restrict__ AO)
{
    __shared__ unsigned short Pl[4][16][40];
    const int lane = threadIdx.x & 63;
    const int w    = threadIdx.x >> 6;
    const int bh   = blockIdx.y;                 // 0..31
    const int q0   = blockIdx.x * 64 + w * 16;
    const unsigned short* Qp = Qb + (size_t)bh * T_SEQ * HDIM;
    const unsigned short* Kp = Kb + (size_t)bh * T_SEQ * HDIM;
    const unsigned short* Vp = Vt + (size_t)bh * HDIM * T_SEQ;
    const int rl = lane & 15;
    const int kq = (lane >> 4) * 8;
    const int rg0 = q0 + (lane >> 4) * 4;        // global q-row of acc reg 0

    bf16x8 qf[2];
    qf[0] = *(const bf16x8*)(Qp + (size_t)(q0 + rl) * HDIM + kq);
    qf[1] = *(const bf16x8*)(Qp + (size_t)(q0 + rl) * HDIM + 32 + kq);

    float m_run[4] = {-INFINITY, -INFINITY, -INFINITY, -INFINITY};
    float l_run[4] = {0.f, 0.f, 0.f, 0.f};
    f32x4 o_acc[4] = {};

    for (int c0 = 0; c0 <= q0 + 15; c0 += 32) {
        // S = Q @ K^T for 16 q-rows x 32 kv-cols
        f32x4 s0 = {}, s1 = {};
        #pragma unroll
        for (int kk = 0; kk < 2; kk++) {
            bf16x8 kf0 = *(const bf16x8*)(Kp + (size_t)(c0 + rl) * HDIM + kk*32 + kq);
            bf16x8 kf1 = *(const bf16x8*)(Kp + (size_t)(c0 + 16 + rl) * HDIM + kk*32 + kq);
            s0 = __builtin_amdgcn_mfma_f32_16x16x32_bf16(qf[kk], kf0, s0, 0, 0, 0);
            s1 = __builtin_amdgcn_mfma_f32_16x16x32_bf16(qf[kk], kf1, s1, 0, 0, 0);
        }
        const int cc0 = c0 + rl, cc1 = c0 + 16 + rl;
        float sf[4];
        #pragma unroll
        for (int r = 0; r < 4; r++) {
            float pm0 = (cc0 > rg0 + r) ? -INFINITY : s0[r] * ATT_SCALE;
            float pm1 = (cc1 > rg0 + r) ? -INFINITY : s1[r] * ATT_SCALE;
            // row max over 16 lanes (cols)
            float tm = fmaxf(pm0, pm1);
            tm = fmaxf(tm, __shfl_xor(tm, 1));
            tm = fmaxf(tm, __shfl_xor(tm, 2));
            tm = fmaxf(tm, __shfl_xor(tm, 4));
            tm = fmaxf(tm, __shfl_xor(tm, 8));
            float mn = fmaxf(m_run[r], tm);      // finite: col c0 always unmasked
            sf[r] = __expf(m_run[r] - mn);
            m_run[r] = mn;
            float p0 = __expf(pm0 - mn);
            float p1 = __expf(pm1 - mn);
            float rs = p0 + p1;
            rs += __shfl_xor(rs, 1);
            rs += __shfl_xor(rs, 2);
            rs += __shfl_xor(rs, 4);
            rs += __shfl_xor(rs, 8);
            l_run[r] = l_run[r] * sf[r] + rs;
            Pl[w][(lane >> 4) * 4 + r][rl]      = f2bf(p0);
            Pl[w][(lane >> 4) * 4 + r][16 + rl] = f2bf(p1);
        }
        #pragma unroll
        for (int db = 0; db < 4; db++)
            #pragma unroll
            for (int r = 0; r < 4; r++) o_acc[db][r] *= sf[r];
        // O += P @ V  (P from LDS, V^T rows contiguous in t)
        bf16x8 pf = *(const bf16x8*)&Pl[w][rl][kq];
        #pragma unroll
        for (int db = 0; db < 4; db++) {
            bf16x8 vf = *(const bf16x8*)(Vp + (size_t)(db*16 + rl) * T_SEQ + c0 + kq);
            o_acc[db] = __builtin_amdgcn_mfma_f32_16x16x32_bf16(pf, vf, o_acc[db], 0, 0, 0);
        }
    }

    const int b = bh >> 4, h = bh & 15;
    #pragma unroll
    for (int db = 0; db < 4; db++) {
        #pragma unroll
        for (int r = 0; r < 4; r++) {
            int t = q0 + (lane >> 4) * 4 + r;
            float v = o_acc[db][r] / l_run[r];
            AO[((size_t)(b * T_SEQ + t)) * CDIM + h * HDIM + db*16 + rl] = f2bf(v);
        }
    }
}

// ---------------------------------------------------------------------------
extern "C" void kernel_launch(void* const* d_in, const int* in_sizes, int n_in,
                              void* d_out, int out_size, void* d_ws, size_t ws_size,
                              hipStream_t stream) {
    const float* x      = (const float*)d_in[0];
    const float* w_qkv  = (const float*)d_in[1];
    const float* b_qkv  = (const float*)d_in[2];
    const float* w_proj = (const float*)d_in[3];
    const float* b_proj = (const float*)d_in[4];
    float* out = (float*)d_out;

    // workspace: Q,K (B,H,T,D) + V^T (B,H,D,T) + AO (B,T,C), all bf16 = 32 MB
    const size_t NELEM = (size_t)2 * NHEAD * T_SEQ * HDIM;  // 4 Mi elems
    unsigned short* Qb = (unsigned short*)d_ws;
    unsigned short* Kb = Qb + NELEM;
    unsigned short* Vt = Kb + NELEM;
    unsigned short* AO = Vt + NELEM;

    // 1) QKV projection (M=4096, N=3072)
    gemm_k<3072, false, 0><<<dim3(32, 24), 256, 0, stream>>>(
        x, w_qkv, b_qkv, nullptr, Qb, Kb, Vt);
    // 2) causal flash attention
    attn_k<<<dim3(T_SEQ / 64, 2 * NHEAD), 256, 0, stream>>>(Qb, Kb, Vt, AO);
    // 3) output projection (M=4096, N=1024)
    gemm_k<1024, true, 1><<<dim3(32, 8), 256, 0, stream>>>(
        AO, w_proj, b_proj, out, nullptr, nullptr, nullptr);
}

// Round 2
// 208.628 us; speedup vs baseline: 1.5301x; 1.5301x over previous
//
#include <hip/hip_runtime.h>
#include <hip/hip_bf16.h>
#include <math.h>

// Problem constants: B=2, T=2048, C=1024, H=16, D=64
#define T_SEQ 2048
#define NHEAD 16
#define HDIM  64
#define CDIM  1024
#define KDIM  1024
#define ATT_SCALE 0.125f

typedef __attribute__((ext_vector_type(8))) short bf16x8;
typedef __attribute__((ext_vector_type(4))) float f32x4;
typedef __attribute__((ext_vector_type(16))) float f32x16;
typedef __attribute__((ext_vector_type(8))) unsigned short u16x8;
typedef __attribute__((ext_vector_type(4))) unsigned int u32x4;

__device__ __forceinline__ unsigned short f2bf(float f) {
    unsigned int u = __builtin_bit_cast(unsigned int, f);
    u += 0x7fffu + ((u >> 16) & 1u);   // round-to-nearest-even
    return (unsigned short)(u >> 16);
}

// ---------------------------------------------------------------------------
// GEMM: C[4096, NC] = A[4096,1024] @ W[1024, NC] + bias   (unchanged from R0)
// ---------------------------------------------------------------------------
template<int NC, bool ABF16, int EPI>
__global__ __launch_bounds__(256) void gemm_k(
    const void* __restrict__ Ap, const float* __restrict__ W,
    const float* __restrict__ bias, float* __restrict__ Of,
    unsigned short* __restrict__ Qb, unsigned short* __restrict__ Kb,
    unsigned short* __restrict__ Vt)
{
    __shared__ unsigned short As[128][40];  // 40-elem (80B) row stride: 2-way bank alias = free
    __shared__ unsigned short Bs[128][40];  // Bs[n][k] (W tile transposed)

    const int tid  = threadIdx.x;
    const int lane = tid & 63;
    const int wid  = tid >> 6;
    const int m0 = blockIdx.x * 128;
    const int n0 = blockIdx.y * 128;
    const int wm = (wid >> 1) * 64;
    const int wn = (wid & 1) * 64;
    const int rl = lane & 15;
    const int kq = (lane >> 4) * 8;

    f32x4 acc[4][4] = {};

    for (int k0 = 0; k0 < KDIM; k0 += 32) {
        if (!ABF16) {
            const float* Af = (const float*)Ap;
            #pragma unroll
            for (int i = 0; i < 4; i++) {
                int lin = i * 256 + tid;
                int row = lin >> 3;
                int c4  = (lin & 7) * 4;
                float4 v = *(const float4*)(Af + (size_t)(m0 + row) * KDIM + k0 + c4);
                ushort4 h;
                h.x = f2bf(v.x); h.y = f2bf(v.y); h.z = f2bf(v.z); h.w = f2bf(v.w);
                *(ushort4*)&As[row][c4] = h;
            }
        } else {
            const unsigned short* Ah = (const unsigned short*)Ap;
            #pragma unroll
            for (int i = 0; i < 2; i++) {
                int lin = i * 256 + tid;
                int row = lin >> 2;
                int c8  = (lin & 3) * 8;
                u16x8 v = *(const u16x8*)(Ah + (size_t)(m0 + row) * KDIM + k0 + c8);
                *(u16x8*)&As[row][c8] = v;
            }
        }
        {
            int n  = tid & 127;
            int kc = (tid >> 7) * 16;
            u16x8 t0, t1;
            #pragma unroll
            for (int j = 0; j < 8; j++)
                t0[j] = (short)f2bf(W[(size_t)(k0 + kc + j) * NC + n0 + n]);
            #pragma unroll
            for (int j = 0; j < 8; j++)
                t1[j] = (short)f2bf(W[(size_t)(k0 + kc + 8 + j) * NC + n0 + n]);
            *(u16x8*)&Bs[n][kc]     = t0;
            *(u16x8*)&Bs[n][kc + 8] = t1;
        }
        __syncthreads();

        bf16x8 af[4], bfr[4];
        #pragma unroll
        for (int f = 0; f < 4; f++) {
            af[f]  = *(const bf16x8*)&As[wm + f*16 + rl][kq];
            bfr[f] = *(const bf16x8*)&Bs[wn + f*16 + rl][kq];
        }
        #pragma unroll
        for (int i = 0; i < 4; i++)
            #pragma unroll
            for (int j = 0; j < 4; j++)
                acc[i][j] = __builtin_amdgcn_mfma_f32_16x16x32_bf16(af[i], bfr[j], acc[i][j], 0, 0, 0);
        __syncthreads();
    }

    #pragma unroll
    for (int j = 0; j < 4; j++) {
        int gn = n0 + wn + j*16 + rl;
        float bv = bias[gn];
        #pragma unroll
        for (int i = 0; i < 4; i++) {
            int gm0 = m0 + wm + i*16 + (lane >> 4) * 4;
            #pragma unroll
            for (int r = 0; r < 4; r++) {
                float v = acc[i][j][r] + bv;
                int gm = gm0 + r;
                if (EPI == 0) {
                    int which = gn >> 10;
                    int cw = gn & 1023;
                    int h = cw >> 6, d = cw & 63;
                    int b = gm >> 11, t = gm & 2047;
                    size_t bh = (size_t)(b * NHEAD + h);
                    unsigned short hv = f2bf(v);
                    if (which == 0)      Qb[(bh * T_SEQ + t) * HDIM + d] = hv;
                    else if (which == 1) Kb[(bh * T_SEQ + t) * HDIM + d] = hv;
                    else                 Vt[(bh * HDIM + d) * T_SEQ + t] = hv;
                } else {
                    Of[(size_t)gm * NC + gn] = v;
                }
            }
        }
    }
}

// ---------------------------------------------------------------------------
// Causal flash attention, swapped-QK^T 32x32 structure, zero LDS.
// 4 waves/block, each wave owns 32 q-rows (block = 128 q-rows).
// S^T = K·Q^T via mfma_32x32x16: lane holds 16 S-values of ONE q-row
// (q = lane&31, kv rows (r&3)+8*(r>>2)+4*hi) -> scalar online softmax.
// P packed to bf16 in-register, one shfl_xor(32) per dword pair to build
// PV B-frags. PV: O^T = V^T·P^T from Vt[D][T] (contiguous frags).
// ---------------------------------------------------------------------------
__global__ __launch_bounds__(256) void attn_k(
    const unsigned short* __restrict__ Qb, const unsigned short* __restrict__ Kb,
    const unsigned short* __restrict__ Vt, unsigned short* __restrict__ AO)
{
    const int lane = threadIdx.x & 63;
    const int w    = threadIdx.x >> 6;
    const int bh   = blockIdx.y;
    const int qt   = gridDim.x - 1 - blockIdx.x;   // heavy q-tiles dispatched first
    const int q0w  = qt * 128 + w * 32;
    const int ql   = lane & 31;
    const int hi   = lane >> 5;
    const int qg   = q0w + ql;                      // this lane's q-row

    const unsigned short* Qp = Qb + (size_t)bh * T_SEQ * HDIM;
    const unsigned short* Kp = Kb + (size_t)bh * T_SEQ * HDIM;
    const unsigned short* Vp = Vt + (size_t)bh * HDIM * T_SEQ;

    // Q fragments (held all kernel): Q[qg][dc*16 + hi*8 + 0..7]
    bf16x8 qf[4];
    #pragma unroll
    for (int dc = 0; dc < 4; dc++)
        qf[dc] = *(const bf16x8*)(Qp + (size_t)qg * HDIM + dc*16 + hi*8);

    float m_run = -INFINITY, l_run = 0.f;
    f32x16 o0 = {}, o1 = {};

    const int ntiles = (q0w >> 5) + 1;
    for (int it = 0; it < ntiles; ++it) {
        const int c0 = it << 5;
        // ---- S^T[kv][q] = K·Q^T, 32kv x 32q, K-dim = D in 4 chunks of 16 ----
        f32x16 s = {};
        #pragma unroll
        for (int dc = 0; dc < 4; dc++) {
            bf16x8 kf = *(const bf16x8*)(Kp + (size_t)(c0 + ql) * HDIM + dc*16 + hi*8);
            s = __builtin_amdgcn_mfma_f32_32x32x16_bf16(kf, qf[dc], s, 0, 0, 0);
        }
        // ---- lane-local online softmax (q = lane&31) ----
        float pm[16];
        #pragma unroll
        for (int r = 0; r < 16; r++) pm[r] = s[r] * ATT_SCALE;
        if (c0 == q0w) {                            // diagonal tile only
            #pragma unroll
            for (int r = 0; r < 16; r++) {
                int kv = c0 + (r & 3) + 8 * (r >> 2) + 4 * hi;
                pm[r] = (kv > qg) ? -INFINITY : pm[r];
            }
        }
        float tm = pm[0];
        #pragma unroll
        for (int r = 1; r < 16; r++) tm = fmaxf(tm, pm[r]);
        tm = fmaxf(tm, __shfl_xor(tm, 32));         // lane and lane+32: same q
        float mn = fmaxf(m_run, tm);
        float sf = __expf(m_run - mn);
        m_run = mn;
        float p[16];
        float rs = 0.f;
        #pragma unroll
        for (int r = 0; r < 16; r++) { p[r] = __expf(pm[r] - mn); rs += p[r]; }
        rs += __shfl_xor(rs, 32);
        l_run = l_run * sf + rs;
        #pragma unroll
        for (int r = 0; r < 16; r++) { o0[r] *= sf; o1[r] *= sf; }

        // ---- pack P to bf16 dwords; redistribute halves for PV B-frags ----
        // lane holds kv rows {(r&3)+8*(r>>2)+4*hi}; B-frag needs kv = kc*16+hi*8+j
        unsigned int c[8], x[8];
        #pragma unroll
        for (int i = 0; i < 8; i++)
            c[i] = (unsigned int)f2bf(p[2*i]) | ((unsigned int)f2bf(p[2*i+1]) << 16);
        #pragma unroll
        for (int i = 0; i < 8; i++) x[i] = __shfl_xor(c[i], 32);

        u32x4 b0, b1;
        b0[0] = hi ? x[2] : c[0];   // kc=0: hi0 kv{0,1},  hi1 kv{8,9}
        b0[1] = hi ? x[3] : c[1];   //       hi0 kv{2,3},  hi1 kv{10,11}
        b0[2] = hi ? c[2] : x[0];   //       hi0 kv{4,5},  hi1 kv{12,13}
        b0[3] = hi ? c[3] : x[1];   //       hi0 kv{6,7},  hi1 kv{14,15}
        b1[0] = hi ? x[6] : c[4];   // kc=1: hi0 kv{16,17},hi1 kv{24,25}
        b1[1] = hi ? x[7] : c[5];
        b1[2] = hi ? c[6] : x[4];
        b1[3] = hi ? c[7] : x[5];
        bf16x8 pf0 = __builtin_bit_cast(bf16x8, b0);
        bf16x8 pf1 = __builtin_bit_cast(bf16x8, b1);

        // ---- O^T[d][q] += V^T[d][kv] · P^T[kv][q] ----
        const unsigned short* vb0 = Vp + (size_t)ql * T_SEQ + c0 + hi*8;
        const unsigned short* vb1 = vb0 + (size_t)32 * T_SEQ;
        bf16x8 v00 = *(const bf16x8*)(vb0);
        bf16x8 v01 = *(const bf16x8*)(vb0 + 16);
        bf16x8 v10 = *(const bf16x8*)(vb1);
        bf16x8 v11 = *(const bf16x8*)(vb1 + 16);
        o0 = __builtin_amdgcn_mfma_f32_32x32x16_bf16(v00, pf0, o0, 0, 0, 0);
        o0 = __builtin_amdgcn_mfma_f32_32x32x16_bf16(v01, pf1, o0, 0, 0, 0);
        o1 = __builtin_amdgcn_mfma_f32_32x32x16_bf16(v10, pf0, o1, 0, 0, 0);
        o1 = __builtin_amdgcn_mfma_f32_32x32x16_bf16(v11, pf1, o1, 0, 0, 0);
    }

    // ---- epilogue: O^T[d][q] -> AO[b, t=qg, h*64+d] ----
    const float inv_l = 1.f / l_run;
    const int b = bh >> 4, h = bh & 15;
    unsigned short* aop = AO + ((size_t)(b * T_SEQ + qg)) * CDIM + h * HDIM;
    #pragma unroll
    for (int r = 0; r < 16; r++) {
        int d = (r & 3) + 8 * (r >> 2) + 4 * hi;
        aop[d]      = f2bf(o0[r] * inv_l);
        aop[d + 32] = f2bf(o1[r] * inv_l);
    }
}

// ---------------------------------------------------------------------------
extern "C" void kernel_launch(void* const* d_in, const int* in_sizes, int n_in,
                              void* d_out, int out_size, void* d_ws, size_t ws_size,
                              hipStream_t stream) {
    const float* x      = (const float*)d_in[0];
    const float* w_qkv  = (const float*)d_in[1];
    const float* b_qkv  = (const float*)d_in[2];
    const float* w_proj = (const float*)d_in[3];
    const float* b_proj = (const float*)d_in[4];
    float* out = (float*)d_out;

    const size_t NELEM = (size_t)2 * NHEAD * T_SEQ * HDIM;  // 4 Mi elems
    unsigned short* Qb = (unsigned short*)d_ws;
    unsigned short* Kb = Qb + NELEM;
    unsigned short* Vt = Kb + NELEM;
    unsigned short* AO = Vt + NELEM;

    // 1) QKV projection (M=4096, N=3072)
    gemm_k<3072, false, 0><<<dim3(32, 24), 256, 0, stream>>>(
        x, w_qkv, b_qkv, nullptr, Qb, Kb, Vt);
    // 2) causal flash attention (swapped-QK^T 32x32, zero LDS)
    attn_k<<<dim3(T_SEQ / 128, 2 * NHEAD), 256, 0, stream>>>(Qb, Kb, Vt, AO);
    // 3) output projection (M=4096, N=1024)
    gemm_k<1024, true, 1><<<dim3(32, 8), 256, 0, stream>>>(
        AO, w_proj, b_proj, out, nullptr, nullptr, nullptr);
}

// Round 3
// 202.346 us; speedup vs baseline: 1.5776x; 1.0310x over previous
//
#include <hip/hip_runtime.h>
#include <hip/hip_bf16.h>
#include <math.h>

// Problem constants: B=2, T=2048, C=1024, H=16, D=64
#define T_SEQ 2048
#define NHEAD 16
#define HDIM  64
#define CDIM  1024
#define KDIM  1024
// softmax runs in exp2 domain; SCALE*log2(e) folded into Q at GEMM epilogue
#define SCALE_L2E 0.1803368801111204f

typedef __attribute__((ext_vector_type(8))) short bf16x8;
typedef __attribute__((ext_vector_type(4))) float f32x4;
typedef __attribute__((ext_vector_type(16))) float f32x16;
typedef __attribute__((ext_vector_type(8))) unsigned short u16x8;
typedef __attribute__((ext_vector_type(4))) unsigned int u32x4;

__device__ __forceinline__ unsigned short f2bf(float f) {
    unsigned int u = __builtin_bit_cast(unsigned int, f);
    u += 0x7fffu + ((u >> 16) & 1u);   // round-to-nearest-even
    return (unsigned short)(u >> 16);
}
__device__ __forceinline__ unsigned int cvt_pk_bf16(float lo, float hi_) {
    unsigned int r;
    asm("v_cvt_pk_bf16_f32 %0, %1, %2" : "=v"(r) : "v"(lo), "v"(hi_));
    return r;
}
// a' = {a.lo, b.lo-from-paired-half}; b' = {a.hi-from-paired-half, b.hi}
__device__ __forceinline__ void pl32swap(unsigned int &a, unsigned int &b) {
    asm("v_permlane32_swap_b32 %0, %1" : "+v"(a), "+v"(b));
}

// ---------------------------------------------------------------------------
// prep: x f32 -> bf16 (same layout)
// ---------------------------------------------------------------------------
__global__ __launch_bounds__(256) void prep_x(const float* __restrict__ x,
                                              unsigned short* __restrict__ Xb) {
    size_t i = ((size_t)blockIdx.x * 256 + threadIdx.x) * 8;
    float4 a = *(const float4*)(x + i);
    float4 b = *(const float4*)(x + i + 4);
    u32x4 o;
    o[0] = cvt_pk_bf16(a.x, a.y);
    o[1] = cvt_pk_bf16(a.z, a.w);
    o[2] = cvt_pk_bf16(b.x, b.y);
    o[3] = cvt_pk_bf16(b.z, b.w);
    *(u32x4*)(Xb + i) = o;
}

// ---------------------------------------------------------------------------
// prep: W f32 [K=1024][NC] -> Wt bf16 [NC][1024]  (64x64 LDS tile transpose)
// ---------------------------------------------------------------------------
template<int NC>
__global__ __launch_bounds__(256) void prep_w(const float* __restrict__ W,
                                              unsigned short* __restrict__ Wt) {
    __shared__ unsigned short Ls[64][72];
    const int n0 = blockIdx.x * 64, k0 = blockIdx.y * 64;
    const int t = threadIdx.x;
    {
        int kr = t >> 2, nc = (t & 3) * 16;
        #pragma unroll
        for (int j = 0; j < 4; j++) {
            float4 v = *(const float4*)(W + (size_t)(k0 + kr) * NC + n0 + nc + j * 4);
            Ls[nc + j*4 + 0][kr] = f2bf(v.x);
            Ls[nc + j*4 + 1][kr] = f2bf(v.y);
            Ls[nc + j*4 + 2][kr] = f2bf(v.z);
            Ls[nc + j*4 + 3][kr] = f2bf(v.w);
        }
    }
    __syncthreads();
    {
        int nr = t >> 2, kc = (t & 3) * 16;
        u16x8 o0 = *(const u16x8*)&Ls[nr][kc];
        u16x8 o1 = *(const u16x8*)&Ls[nr][kc + 8];
        *(u16x8*)(Wt + (size_t)(n0 + nr) * KDIM + k0 + kc)     = o0;
        *(u16x8*)(Wt + (size_t)(n0 + nr) * KDIM + k0 + kc + 8) = o1;
    }
}

// ---------------------------------------------------------------------------
// GEMM: C[4096, NC] = A[4096,1024]bf16 @ Wt[NC,1024]bf16^T + bias
// Tile 128x128, 4 waves (2x2 of 64x64), BK=64, mfma_f32_16x16x32_bf16.
//  EPI 0: route to Q (scaled by SCALE_L2E), K, V^T as bf16 (NC=3072)
//  EPI 1: fp32 store to Of (NC=1024)
// ---------------------------------------------------------------------------
template<int NC, int EPI>
__global__ __launch_bounds__(256) void gemm_k(
    const unsigned short* __restrict__ A, const unsigned short* __restrict__ Wt,
    const float* __restrict__ bias, float* __restrict__ Of,
    unsigned short* __restrict__ Qb, unsigned short* __restrict__ Kb,
    unsigned short* __restrict__ Vt)
{
    __shared__ unsigned short As[128][72];  // 144B row stride: 2-way alias = free
    __shared__ unsigned short Bs[128][72];

    const int tid  = threadIdx.x;
    const int lane = tid & 63;
    const int wid  = tid >> 6;
    const int m0 = blockIdx.x * 128;
    const int n0 = blockIdx.y * 128;
    const int wm = (wid >> 1) * 64;
    const int wn = (wid & 1) * 64;
    const int rl = lane & 15;
    const int kq = (lane >> 4) * 8;

    f32x4 acc[4][4] = {};

    for (int k0 = 0; k0 < KDIM; k0 += 64) {
        #pragma unroll
        for (int i = 0; i < 4; i++) {
            int lin = i * 256 + tid;           // 0..1023
            int row = lin >> 3;                // 8 chunks of 8 bf16 per row
            int c8  = (lin & 7) * 8;
            *(u16x8*)&As[row][c8] = *(const u16x8*)(A  + (size_t)(m0 + row) * KDIM + k0 + c8);
            *(u16x8*)&Bs[row][c8] = *(const u16x8*)(Wt + (size_t)(n0 + row) * KDIM + k0 + c8);
        }
        __syncthreads();
        #pragma unroll
        for (int kc = 0; kc < 2; kc++) {
            bf16x8 af[4], bfr[4];
            #pragma unroll
            for (int f = 0; f < 4; f++) {
                af[f]  = *(const bf16x8*)&As[wm + f*16 + rl][kc*32 + kq];
                bfr[f] = *(const bf16x8*)&Bs[wn + f*16 + rl][kc*32 + kq];
            }
            #pragma unroll
            for (int i = 0; i < 4; i++)
                #pragma unroll
                for (int j = 0; j < 4; j++)
                    acc[i][j] = __builtin_amdgcn_mfma_f32_16x16x32_bf16(af[i], bfr[j], acc[i][j], 0, 0, 0);
        }
        __syncthreads();
    }

    #pragma unroll
    for (int j = 0; j < 4; j++) {
        int gn = n0 + wn + j*16 + rl;
        float bv = bias[gn];
        #pragma unroll
        for (int i = 0; i < 4; i++) {
            int gm0 = m0 + wm + i*16 + (lane >> 4) * 4;
            #pragma unroll
            for (int r = 0; r < 4; r++) {
                float v = acc[i][j][r] + bv;
                int gm = gm0 + r;
                if (EPI == 0) {
                    int which = gn >> 10;          // 0=q 1=k 2=v
                    int cw = gn & 1023;
                    int h = cw >> 6, d = cw & 63;
                    int b = gm >> 11, t = gm & 2047;
                    size_t bh = (size_t)(b * NHEAD + h);
                    if (which == 0)      Qb[(bh * T_SEQ + t) * HDIM + d] = f2bf(v * SCALE_L2E);
                    else if (which == 1) Kb[(bh * T_SEQ + t) * HDIM + d] = f2bf(v);
                    else                 Vt[(bh * HDIM + d) * T_SEQ + t] = f2bf(v);
                } else {
                    Of[(size_t)gm * NC + gn] = v;
                }
            }
        }
    }
}

// ---------------------------------------------------------------------------
// Causal flash attention, swapped-QK^T 32x32, zero LDS, exp2-domain softmax,
// defer-max rescale, cvt_pk+permlane32_swap P packing, K/V prefetch.
// ---------------------------------------------------------------------------
__global__ __launch_bounds__(256) void attn_k(
    const unsigned short* __restrict__ Qb, const unsigned short* __restrict__ Kb,
    const unsigned short* __restrict__ Vt, unsigned short* __restrict__ AO)
{
    const int lane = threadIdx.x & 63;
    const int w    = threadIdx.x >> 6;
    const int bh   = blockIdx.y;
    const int qt   = gridDim.x - 1 - blockIdx.x;   // heavy q-tiles first
    const int q0w  = qt * 128 + w * 32;
    const int ql   = lane & 31;
    const int hi   = lane >> 5;
    const int qg   = q0w + ql;

    const unsigned short* Qp = Qb + (size_t)bh * T_SEQ * HDIM;
    const unsigned short* Kp = Kb + (size_t)bh * T_SEQ * HDIM;
    const unsigned short* Vp = Vt + (size_t)bh * HDIM * T_SEQ;

    bf16x8 qf[4];
    #pragma unroll
    for (int dc = 0; dc < 4; dc++)
        qf[dc] = *(const bf16x8*)(Qp + (size_t)qg * HDIM + dc*16 + hi*8);

    float m_run = -INFINITY, l_run = 0.f;
    f32x16 o0 = {}, o1 = {};

    const int ntiles = (q0w >> 5) + 1;
    bf16x8 kf[4];
    #pragma unroll
    for (int dc = 0; dc < 4; dc++)
        kf[dc] = *(const bf16x8*)(Kp + (size_t)ql * HDIM + dc*16 + hi*8);

    for (int it = 0; it < ntiles; ++it) {
        const int c0 = it << 5;
        // ---- S^T[kv][q] = K·(Q*scale)^T ----
        f32x16 s = {};
        #pragma unroll
        for (int dc = 0; dc < 4; dc++)
            s = __builtin_amdgcn_mfma_f32_32x32x16_bf16(kf[dc], qf[dc], s, 0, 0, 0);
        // ---- prefetch V (current tile) and K (next tile): hide under softmax
        const unsigned short* vb0 = Vp + (size_t)ql * T_SEQ + c0 + hi*8;
        bf16x8 v00 = *(const bf16x8*)(vb0);
        bf16x8 v01 = *(const bf16x8*)(vb0 + 16);
        bf16x8 v10 = *(const bf16x8*)(vb0 + (size_t)32 * T_SEQ);
        bf16x8 v11 = *(const bf16x8*)(vb0 + (size_t)32 * T_SEQ + 16);
        if (it + 1 < ntiles) {
            const unsigned short* kb = Kp + (size_t)(c0 + 32 + ql) * HDIM + hi*8;
            #pragma unroll
            for (int dc = 0; dc < 4; dc++)
                kf[dc] = *(const bf16x8*)(kb + dc*16);
        }
        // ---- lane-local online softmax (exp2 domain; q = lane&31) ----
        float pm[16];
        #pragma unroll
        for (int r = 0; r < 16; r++) pm[r] = s[r];
        if (c0 == q0w) {                            // diagonal tile only
            #pragma unroll
            for (int r = 0; r < 16; r++) {
                int kv = c0 + (r & 3) + 8 * (r >> 2) + 4 * hi;
                pm[r] = (kv > qg) ? -INFINITY : pm[r];
            }
        }
        float t0 = fmaxf(fmaxf(pm[0],  pm[1]),  pm[2]);
        float t1 = fmaxf(fmaxf(pm[3],  pm[4]),  pm[5]);
        float t2 = fmaxf(fmaxf(pm[6],  pm[7]),  pm[8]);
        float t3 = fmaxf(fmaxf(pm[9],  pm[10]), pm[11]);
        float t4 = fmaxf(fmaxf(pm[12], pm[13]), pm[14]);
        float tm = fmaxf(fmaxf(fmaxf(t0, t1), t2), fmaxf(fmaxf(t3, t4), pm[15]));
        tm = fmaxf(tm, __shfl_xor(tm, 32));         // lane & lane+32: same q
        if (__any(tm > m_run + 11.5f)) {            // defer-max: e^8 in log2
            float mn = fmaxf(m_run, tm);
            float sf = exp2f(m_run - mn);
            m_run = mn;
            l_run *= sf;
            #pragma unroll
            for (int r = 0; r < 16; r++) { o0[r] *= sf; o1[r] *= sf; }
        }
        float p[16]; float rs = 0.f;
        #pragma unroll
        for (int r = 0; r < 16; r++) { p[r] = exp2f(pm[r] - m_run); rs += p[r]; }
        rs += __shfl_xor(rs, 32);
        l_run += rs;

        // ---- pack P to bf16 PV B-frags: 8 cvt_pk + 4 permlane32_swap ----
        unsigned int c[8];
        #pragma unroll
        for (int i = 0; i < 8; i++)
            c[i] = cvt_pk_bf16(p[2*i], p[2*i+1]);
        pl32swap(c[0], c[2]);  pl32swap(c[1], c[3]);
        pl32swap(c[4], c[6]);  pl32swap(c[5], c[7]);
        u32x4 b0 = {c[0], c[1], c[2], c[3]};
        u32x4 b1 = {c[4], c[5], c[6], c[7]};
        bf16x8 pf0 = __builtin_bit_cast(bf16x8, b0);
        bf16x8 pf1 = __builtin_bit_cast(bf16x8, b1);

        // ---- O^T[d][q] += V^T[d][kv] · P^T[kv][q] ----
        o0 = __builtin_amdgcn_mfma_f32_32x32x16_bf16(v00, pf0, o0, 0, 0, 0);
        o0 = __builtin_amdgcn_mfma_f32_32x32x16_bf16(v01, pf1, o0, 0, 0, 0);
        o1 = __builtin_amdgcn_mfma_f32_32x32x16_bf16(v10, pf0, o1, 0, 0, 0);
        o1 = __builtin_amdgcn_mfma_f32_32x32x16_bf16(v11, pf1, o1, 0, 0, 0);
    }

    // ---- epilogue: O^T[d][q] -> AO[b, t=qg, h*64+d], packed 8B stores ----
    const float inv_l = 1.f / l_run;
    const int b = bh >> 4, h = bh & 15;
    unsigned short* aop = AO + ((size_t)(b * T_SEQ + qg)) * CDIM + h * HDIM;
    #pragma unroll
    for (int qd = 0; qd < 4; qd++) {
        uint2 w0, w1;
        w0.x = cvt_pk_bf16(o0[4*qd+0] * inv_l, o0[4*qd+1] * inv_l);
        w0.y = cvt_pk_bf16(o0[4*qd+2] * inv_l, o0[4*qd+3] * inv_l);
        w1.x = cvt_pk_bf16(o1[4*qd+0] * inv_l, o1[4*qd+1] * inv_l);
        w1.y = cvt_pk_bf16(o1[4*qd+2] * inv_l, o1[4*qd+3] * inv_l);
        *(uint2*)(aop + qd*8 + hi*4)      = w0;
        *(uint2*)(aop + 32 + qd*8 + hi*4) = w1;
    }
}

// ---------------------------------------------------------------------------
extern "C" void kernel_launch(void* const* d_in, const int* in_sizes, int n_in,
                              void* d_out, int out_size, void* d_ws, size_t ws_size,
                              hipStream_t stream) {
    const float* x      = (const float*)d_in[0];
    const float* w_qkv  = (const float*)d_in[1];
    const float* b_qkv  = (const float*)d_in[2];
    const float* w_proj = (const float*)d_in[3];
    const float* b_proj = (const float*)d_in[4];
    float* out = (float*)d_out;

    // ws layout (ushort elems): Q 4Mi | K 4Mi | V^T 4Mi | Wqkv^T 3Mi | Wproj^T 1Mi
    //                           | Xb 4Mi (overlaid by AO after QKV gemm) = 40 MB
    const size_t MI = (size_t)1 << 20;
    unsigned short* base = (unsigned short*)d_ws;
    unsigned short* Qb  = base;
    unsigned short* Kb  = base + 4*MI;
    unsigned short* Vt  = base + 8*MI;
    unsigned short* Wqt = base + 12*MI;
    unsigned short* Wpt = base + 15*MI;
    unsigned short* Xb  = base + 16*MI;
    unsigned short* AO  = Xb;   // Xb dead after QKV gemm; attn writes AO after

    // 0) dtype prep
    prep_x<<<dim3(2048), 256, 0, stream>>>(x, Xb);
    prep_w<3072><<<dim3(48, 16), 256, 0, stream>>>(w_qkv, Wqt);
    prep_w<1024><<<dim3(16, 16), 256, 0, stream>>>(w_proj, Wpt);
    // 1) QKV projection (M=4096, N=3072)
    gemm_k<3072, 0><<<dim3(32, 24), 256, 0, stream>>>(
        Xb, Wqt, b_qkv, nullptr, Qb, Kb, Vt);
    // 2) causal flash attention
    attn_k<<<dim3(T_SEQ / 128, 2 * NHEAD), 256, 0, stream>>>(Qb, Kb, Vt, AO);
    // 3) output projection (M=4096, N=1024)
    gemm_k<1024, 1><<<dim3(32, 8), 256, 0, stream>>>(
        AO, Wpt, b_proj, out, nullptr, nullptr, nullptr);
}

// Round 4
// 161.740 us; speedup vs baseline: 1.9737x; 1.2511x over previous
//
#include <hip/hip_runtime.h>
#include <hip/hip_bf16.h>
#include <math.h>

// Problem constants: B=2, T=2048, C=1024, H=16, D=64
#define T_SEQ 2048
#define NHEAD 16
#define HDIM  64
#define CDIM  1024
#define KDIM  1024
// softmax runs in exp2 domain; SCALE*log2(e) folded into Q at GEMM epilogue
#define SCALE_L2E 0.1803368801111204f

typedef __attribute__((ext_vector_type(8))) short bf16x8;
typedef __attribute__((ext_vector_type(4))) float f32x4;
typedef __attribute__((ext_vector_type(16))) float f32x16;
typedef __attribute__((ext_vector_type(8))) unsigned short u16x8;
typedef __attribute__((ext_vector_type(4))) unsigned int u32x4;

__device__ __forceinline__ unsigned short f2bf(float f) {
    unsigned int u = __builtin_bit_cast(unsigned int, f);
    u += 0x7fffu + ((u >> 16) & 1u);   // round-to-nearest-even
    return (unsigned short)(u >> 16);
}
__device__ __forceinline__ unsigned int cvt_pk_bf16(float lo, float hi_) {
    unsigned int r;
    asm("v_cvt_pk_bf16_f32 %0, %1, %2" : "=v"(r) : "v"(lo), "v"(hi_));
    return r;
}
__device__ __forceinline__ void pl32swap(unsigned int &a, unsigned int &b) {
    asm("v_permlane32_swap_b32 %0, %1" : "+v"(a), "+v"(b));
}
// async global->LDS, 16B per lane; LDS dest is wave-uniform base + lane*16
__device__ __forceinline__ void gld16(const unsigned short* g, unsigned short* l) {
    __builtin_amdgcn_global_load_lds(
        (const __attribute__((address_space(1))) unsigned int*)g,
        (__attribute__((address_space(3))) unsigned int*)l,
        16, 0, 0);
}

// ---------------------------------------------------------------------------
// prep: x f32 -> bf16 (same layout)
// ---------------------------------------------------------------------------
__global__ __launch_bounds__(256) void prep_x(const float* __restrict__ x,
                                              unsigned short* __restrict__ Xb) {
    size_t i = ((size_t)blockIdx.x * 256 + threadIdx.x) * 8;
    float4 a = *(const float4*)(x + i);
    float4 b = *(const float4*)(x + i + 4);
    u32x4 o;
    o[0] = cvt_pk_bf16(a.x, a.y);
    o[1] = cvt_pk_bf16(a.z, a.w);
    o[2] = cvt_pk_bf16(b.x, b.y);
    o[3] = cvt_pk_bf16(b.z, b.w);
    *(u32x4*)(Xb + i) = o;
}

// ---------------------------------------------------------------------------
// prep: W f32 [K=1024][NC] -> Wt bf16 [NC][1024]  (64x64 LDS tile transpose)
// ---------------------------------------------------------------------------
template<int NC>
__global__ __launch_bounds__(256) void prep_w(const float* __restrict__ W,
                                              unsigned short* __restrict__ Wt) {
    __shared__ unsigned short Ls[64][72];
    const int n0 = blockIdx.x * 64, k0 = blockIdx.y * 64;
    const int t = threadIdx.x;
    {
        int kr = t >> 2, nc = (t & 3) * 16;
        #pragma unroll
        for (int j = 0; j < 4; j++) {
            float4 v = *(const float4*)(W + (size_t)(k0 + kr) * NC + n0 + nc + j * 4);
            Ls[nc + j*4 + 0][kr] = f2bf(v.x);
            Ls[nc + j*4 + 1][kr] = f2bf(v.y);
            Ls[nc + j*4 + 2][kr] = f2bf(v.z);
            Ls[nc + j*4 + 3][kr] = f2bf(v.w);
        }
    }
    __syncthreads();
    {
        int nr = t >> 2, kc = (t & 3) * 16;
        u16x8 o0 = *(const u16x8*)&Ls[nr][kc];
        u16x8 o1 = *(const u16x8*)&Ls[nr][kc + 8];
        *(u16x8*)(Wt + (size_t)(n0 + nr) * KDIM + k0 + kc)     = o0;
        *(u16x8*)(Wt + (size_t)(n0 + nr) * KDIM + k0 + kc + 8) = o1;
    }
}

// ---------------------------------------------------------------------------
// GEMM: C[4096, NC] = A[4096,1024]bf16 @ Wt[NC,1024]bf16^T + bias
// Tile 128x128, 4 waves (2x2 of 64x64), BK=64, mfma_f32_16x16x32_bf16.
// ---------------------------------------------------------------------------
template<int NC, int EPI>
__global__ __launch_bounds__(256) void gemm_k(
    const unsigned short* __restrict__ A, const unsigned short* __restrict__ Wt,
    const float* __restrict__ bias, float* __restrict__ Of,
    unsigned short* __restrict__ Qb, unsigned short* __restrict__ Kb,
    unsigned short* __restrict__ Vt)
{
    __shared__ unsigned short As[128][72];
    __shared__ unsigned short Bs[128][72];

    const int tid  = threadIdx.x;
    const int lane = tid & 63;
    const int wid  = tid >> 6;
    const int m0 = blockIdx.x * 128;
    const int n0 = blockIdx.y * 128;
    const int wm = (wid >> 1) * 64;
    const int wn = (wid & 1) * 64;
    const int rl = lane & 15;
    const int kq = (lane >> 4) * 8;

    f32x4 acc[4][4] = {};

    for (int k0 = 0; k0 < KDIM; k0 += 64) {
        #pragma unroll
        for (int i = 0; i < 4; i++) {
            int lin = i * 256 + tid;
            int row = lin >> 3;
            int c8  = (lin & 7) * 8;
            *(u16x8*)&As[row][c8] = *(const u16x8*)(A  + (size_t)(m0 + row) * KDIM + k0 + c8);
            *(u16x8*)&Bs[row][c8] = *(const u16x8*)(Wt + (size_t)(n0 + row) * KDIM + k0 + c8);
        }
        __syncthreads();
        #pragma unroll
        for (int kc = 0; kc < 2; kc++) {
            bf16x8 af[4], bfr[4];
            #pragma unroll
            for (int f = 0; f < 4; f++) {
                af[f]  = *(const bf16x8*)&As[wm + f*16 + rl][kc*32 + kq];
                bfr[f] = *(const bf16x8*)&Bs[wn + f*16 + rl][kc*32 + kq];
            }
            #pragma unroll
            for (int i = 0; i < 4; i++)
                #pragma unroll
                for (int j = 0; j < 4; j++)
                    acc[i][j] = __builtin_amdgcn_mfma_f32_16x16x32_bf16(af[i], bfr[j], acc[i][j], 0, 0, 0);
        }
        __syncthreads();
    }

    #pragma unroll
    for (int j = 0; j < 4; j++) {
        int gn = n0 + wn + j*16 + rl;
        float bv = bias[gn];
        #pragma unroll
        for (int i = 0; i < 4; i++) {
            int gm0 = m0 + wm + i*16 + (lane >> 4) * 4;
            #pragma unroll
            for (int r = 0; r < 4; r++) {
                float v = acc[i][j][r] + bv;
                int gm = gm0 + r;
                if (EPI == 0) {
                    int which = gn >> 10;          // 0=q 1=k 2=v
                    int cw = gn & 1023;
                    int h = cw >> 6, d = cw & 63;
                    int b = gm >> 11, t = gm & 2047;
                    size_t bh = (size_t)(b * NHEAD + h);
                    if (which == 0)      Qb[(bh * T_SEQ + t) * HDIM + d] = f2bf(v * SCALE_L2E);
                    else if (which == 1) Kb[(bh * T_SEQ + t) * HDIM + d] = f2bf(v);
                    else                 Vt[(bh * HDIM + d) * T_SEQ + t] = f2bf(v);
                } else {
                    Of[(size_t)gm * NC + gn] = v;
                }
            }
        }
    }
}

// ---------------------------------------------------------------------------
// Causal flash attention, swapped-QK^T 32x32, block-cooperative LDS K/V
// staging (triple-buffered global_load_lds, counted vmcnt, raw barriers),
// XOR-swizzled LDS (pre-swizzled global source + matching swizzled ds_read).
// Block = 8 waves = 256 q-rows, lockstep kv tiles of 32. Grid 8x32 = 256.
// ---------------------------------------------------------------------------
__global__ __launch_bounds__(512) void attn_k(
    const unsigned short* __restrict__ Qb, const unsigned short* __restrict__ Kb,
    const unsigned short* __restrict__ Vt, unsigned short* __restrict__ AO)
{
    // per tile buffer: K[32 rows][64B swz-segs] = 4KB, then V[64 rows][64B swz] = 4KB
    __shared__ unsigned short sbuf[3 * 4096];

    const int tid  = threadIdx.x;
    const int lane = tid & 63;
    const int w    = tid >> 6;                  // 0..7
    const int bh   = blockIdx.y;                // 0..31
    const int qb   = gridDim.x - 1 - blockIdx.x;
    const int q0w  = qb * 256 + w * 32;
    const int ql   = lane & 31;
    const int hi   = lane >> 5;
    const int qg   = q0w + ql;
    const int nt   = 8 * qb + 8;

    const unsigned short* Qp = Qb + (size_t)bh * T_SEQ * HDIM;
    const unsigned short* Kp = Kb + (size_t)bh * T_SEQ * HDIM;
    const unsigned short* Vp = Vt + (size_t)bh * HDIM * T_SEQ;

    // staging role: waves 0-3 stage K slice (8 rows each), 4-7 stage V (16 rows)
    const unsigned short* sp;
    size_t stepE;   // source elems per kv-tile advance
    int dstoff;     // byte offset of this wave's slice within a tile buffer
    if (w < 4) {
        int row = (w << 3) + (lane >> 3);
        int seg = (lane & 7) ^ (row & 7);       // pre-swizzled source segment
        sp = Kp + (size_t)row * HDIM + seg * 8;
        stepE = 32 * HDIM;
        dstoff = w * 1024;
    } else {
        int row = ((w - 4) << 4) + (lane >> 2);
        int seg = (lane & 3) ^ (row & 3);
        sp = Vp + (size_t)row * T_SEQ + seg * 8;
        stepE = 32;
        dstoff = 4096 + (w - 4) * 1024;
    }

    // Q fragments (held all kernel)
    bf16x8 qf[4];
    #pragma unroll
    for (int dc = 0; dc < 4; dc++)
        qf[dc] = *(const bf16x8*)(Qp + (size_t)qg * HDIM + dc*16 + hi*8);

    float m_run = -INFINITY, l_run = 0.f;
    f32x16 o0 = {}, o1 = {};

    // prologue: stage tiles 0,1,2
    #pragma unroll
    for (int pt = 0; pt < 3; pt++) {
        int ct = pt < nt ? pt : nt - 1;
        gld16(sp + (size_t)ct * stepE,
              (unsigned short*)((char*)sbuf + pt * 8192 + dstoff));
    }

    int bsel = 0;
    for (int t = 0; t < nt; ++t) {
        const int c0 = t << 5;
        asm volatile("s_waitcnt vmcnt(2)" ::: "memory");   // my tile-t slice landed
        __builtin_amdgcn_s_barrier();                      // everyone's landed
        __builtin_amdgcn_sched_barrier(0);

        if (c0 <= q0w) {
            const char* kb = (const char*)sbuf + bsel * 8192;
            const char* vb = kb + 4096;
            // ---- S^T[kv][q] = K·(Q*scale)^T (K from swizzled LDS) ----
            f32x16 s = {};
            #pragma unroll
            for (int dc = 0; dc < 4; dc++) {
                int g = (dc << 1) | hi;
                bf16x8 kf = *(const bf16x8*)(kb + ql*128 + ((g ^ (ql & 7)) << 4));
                s = __builtin_amdgcn_mfma_f32_32x32x16_bf16(kf, qf[dc], s, 0, 0, 0);
            }
            // ---- V frags from swizzled LDS ----
            const int x0 = ((hi)     ^ (ql & 3)) << 4;
            const int x1 = ((2 + hi) ^ (ql & 3)) << 4;
            bf16x8 v00 = *(const bf16x8*)(vb + ql*64 + x0);
            bf16x8 v01 = *(const bf16x8*)(vb + ql*64 + x1);
            bf16x8 v10 = *(const bf16x8*)(vb + 2048 + ql*64 + x0);
            bf16x8 v11 = *(const bf16x8*)(vb + 2048 + ql*64 + x1);

            // ---- lane-local online softmax (exp2 domain; q = lane&31) ----
            float pm[16];
            #pragma unroll
            for (int r = 0; r < 16; r++) pm[r] = s[r];
            if (c0 == q0w) {                       // diagonal tile only
                #pragma unroll
                for (int r = 0; r < 16; r++) {
                    int kv = c0 + (r & 3) + 8 * (r >> 2) + 4 * hi;
                    pm[r] = (kv > qg) ? -INFINITY : pm[r];
                }
            }
            float t0 = fmaxf(fmaxf(pm[0],  pm[1]),  pm[2]);
            float t1 = fmaxf(fmaxf(pm[3],  pm[4]),  pm[5]);
            float t2 = fmaxf(fmaxf(pm[6],  pm[7]),  pm[8]);
            float t3 = fmaxf(fmaxf(pm[9],  pm[10]), pm[11]);
            float t4 = fmaxf(fmaxf(pm[12], pm[13]), pm[14]);
            float tm = fmaxf(fmaxf(fmaxf(t0, t1), t2), fmaxf(fmaxf(t3, t4), pm[15]));
            tm = fmaxf(tm, __shfl_xor(tm, 32));
            if (__any(tm > m_run + 11.5f)) {       // defer-max
                float mn = fmaxf(m_run, tm);
                float sf = exp2f(m_run - mn);
                m_run = mn;
                l_run *= sf;
                #pragma unroll
                for (int r = 0; r < 16; r++) { o0[r] *= sf; o1[r] *= sf; }
            }
            float p[16]; float rs = 0.f;
            #pragma unroll
            for (int r = 0; r < 16; r++) { p[r] = exp2f(pm[r] - m_run); rs += p[r]; }
            rs += __shfl_xor(rs, 32);
            l_run += rs;

            // ---- pack P: 8 cvt_pk + 4 permlane32_swap ----
            unsigned int c[8];
            #pragma unroll
            for (int i = 0; i < 8; i++)
                c[i] = cvt_pk_bf16(p[2*i], p[2*i+1]);
            pl32swap(c[0], c[2]);  pl32swap(c[1], c[3]);
            pl32swap(c[4], c[6]);  pl32swap(c[5], c[7]);
            u32x4 b0 = {c[0], c[1], c[2], c[3]};
            u32x4 b1 = {c[4], c[5], c[6], c[7]};
            bf16x8 pf0 = __builtin_bit_cast(bf16x8, b0);
            bf16x8 pf1 = __builtin_bit_cast(bf16x8, b1);

            // ---- O^T += V^T · P^T ----
            o0 = __builtin_amdgcn_mfma_f32_32x32x16_bf16(v00, pf0, o0, 0, 0, 0);
            o0 = __builtin_amdgcn_mfma_f32_32x32x16_bf16(v01, pf1, o0, 0, 0, 0);
            o1 = __builtin_amdgcn_mfma_f32_32x32x16_bf16(v10, pf0, o1, 0, 0, 0);
            o1 = __builtin_amdgcn_mfma_f32_32x32x16_bf16(v11, pf1, o1, 0, 0, 0);
        }

        __builtin_amdgcn_sched_barrier(0);
        __builtin_amdgcn_s_barrier();              // all done reading buf[bsel]
        int ct = t + 3; if (ct > nt - 1) ct = nt - 1;   // dummy re-stage keeps vmcnt uniform
        gld16(sp + (size_t)ct * stepE,
              (unsigned short*)((char*)sbuf + bsel * 8192 + dstoff));
        if (++bsel == 3) bsel = 0;
    }

    // ---- epilogue: O^T[d][q] -> AO[b, t=qg, h*64+d], packed 8B stores ----
    const float inv_l = 1.f / l_run;
    const int b = bh >> 4, h = bh & 15;
    unsigned short* aop = AO + ((size_t)(b * T_SEQ + qg)) * CDIM + h * HDIM;
    #pragma unroll
    for (int qd = 0; qd < 4; qd++) {
        uint2 w0, w1;
        w0.x = cvt_pk_bf16(o0[4*qd+0] * inv_l, o0[4*qd+1] * inv_l);
        w0.y = cvt_pk_bf16(o0[4*qd+2] * inv_l, o0[4*qd+3] * inv_l);
        w1.x = cvt_pk_bf16(o1[4*qd+0] * inv_l, o1[4*qd+1] * inv_l);
        w1.y = cvt_pk_bf16(o1[4*qd+2] * inv_l, o1[4*qd+3] * inv_l);
        *(uint2*)(aop + qd*8 + hi*4)      = w0;
        *(uint2*)(aop + 32 + qd*8 + hi*4) = w1;
    }
}

// ---------------------------------------------------------------------------
extern "C" void kernel_launch(void* const* d_in, const int* in_sizes, int n_in,
                              void* d_out, int out_size, void* d_ws, size_t ws_size,
                              hipStream_t stream) {
    const float* x      = (const float*)d_in[0];
    const float* w_qkv  = (const float*)d_in[1];
    const float* b_qkv  = (const float*)d_in[2];
    const float* w_proj = (const float*)d_in[3];
    const float* b_proj = (const float*)d_in[4];
    float* out = (float*)d_out;

    const size_t MI = (size_t)1 << 20;
    unsigned short* base = (unsigned short*)d_ws;
    unsigned short* Qb  = base;
    unsigned short* Kb  = base + 4*MI;
    unsigned short* Vt  = base + 8*MI;
    unsigned short* Wqt = base + 12*MI;
    unsigned short* Wpt = base + 15*MI;
    unsigned short* Xb  = base + 16*MI;
    unsigned short* AO  = Xb;   // Xb dead after QKV gemm

    prep_x<<<dim3(2048), 256, 0, stream>>>(x, Xb);
    prep_w<3072><<<dim3(48, 16), 256, 0, stream>>>(w_qkv, Wqt);
    prep_w<1024><<<dim3(16, 16), 256, 0, stream>>>(w_proj, Wpt);
    gemm_k<3072, 0><<<dim3(32, 24), 256, 0, stream>>>(
        Xb, Wqt, b_qkv, nullptr, Qb, Kb, Vt);
    attn_k<<<dim3(8, 32), 512, 0, stream>>>(Qb, Kb, Vt, AO);
    gemm_k<1024, 1><<<dim3(32, 8), 256, 0, stream>>>(
        AO, Wpt, b_proj, out, nullptr, nullptr, nullptr);
}

// Round 5
// 127.195 us; speedup vs baseline: 2.5097x; 1.2716x over previous
//
#include <hip/hip_runtime.h>
#include <hip/hip_bf16.h>
#include <math.h>

// Problem constants: B=2, T=2048, C=1024, H=16, D=64
#define T_SEQ 2048
#define NHEAD 16
#define HDIM  64
#define CDIM  1024
#define KDIM  1024
// softmax runs in exp2 domain; SCALE*log2(e) folded into Q at GEMM epilogue
#define SCALE_L2E 0.1803368801111204f

typedef __attribute__((ext_vector_type(8))) short bf16x8;
typedef __attribute__((ext_vector_type(4))) float f32x4;
typedef __attribute__((ext_vector_type(16))) float f32x16;
typedef __attribute__((ext_vector_type(8))) unsigned short u16x8;
typedef __attribute__((ext_vector_type(4))) unsigned int u32x4;

__device__ __forceinline__ unsigned short f2bf(float f) {
    unsigned int u = __builtin_bit_cast(unsigned int, f);
    u += 0x7fffu + ((u >> 16) & 1u);   // round-to-nearest-even
    return (unsigned short)(u >> 16);
}
__device__ __forceinline__ unsigned int cvt_pk_bf16(float lo, float hi_) {
    unsigned int r;
    asm("v_cvt_pk_bf16_f32 %0, %1, %2" : "=v"(r) : "v"(lo), "v"(hi_));
    return r;
}
__device__ __forceinline__ void pl32swap(unsigned int &a, unsigned int &b) {
    asm("v_permlane32_swap_b32 %0, %1" : "+v"(a), "+v"(b));
}
// async global->LDS, 16B per lane; LDS dest is wave-uniform base + lane*16
__device__ __forceinline__ void gld16(const unsigned short* g, unsigned short* l) {
    __builtin_amdgcn_global_load_lds(
        (const __attribute__((address_space(1))) unsigned int*)g,
        (__attribute__((address_space(3))) unsigned int*)l,
        16, 0, 0);
}

// ---------------------------------------------------------------------------
// prep: x f32 -> bf16 (same layout)
// ---------------------------------------------------------------------------
__global__ __launch_bounds__(256) void prep_x(const float* __restrict__ x,
                                              unsigned short* __restrict__ Xb) {
    size_t i = ((size_t)blockIdx.x * 256 + threadIdx.x) * 8;
    float4 a = *(const float4*)(x + i);
    float4 b = *(const float4*)(x + i + 4);
    u32x4 o;
    o[0] = cvt_pk_bf16(a.x, a.y);
    o[1] = cvt_pk_bf16(a.z, a.w);
    o[2] = cvt_pk_bf16(b.x, b.y);
    o[3] = cvt_pk_bf16(b.z, b.w);
    *(u32x4*)(Xb + i) = o;
}

// ---------------------------------------------------------------------------
// prep: W f32 [K=1024][NC] -> Wt bf16 [NC][1024]  (64x64 LDS tile transpose)
// ---------------------------------------------------------------------------
template<int NC>
__global__ __launch_bounds__(256) void prep_w(const float* __restrict__ W,
                                              unsigned short* __restrict__ Wt) {
    __shared__ unsigned short Ls[64][72];
    const int n0 = blockIdx.x * 64, k0 = blockIdx.y * 64;
    const int t = threadIdx.x;
    {
        int kr = t >> 2, nc = (t & 3) * 16;
        #pragma unroll
        for (int j = 0; j < 4; j++) {
            float4 v = *(const float4*)(W + (size_t)(k0 + kr) * NC + n0 + nc + j * 4);
            Ls[nc + j*4 + 0][kr] = f2bf(v.x);
            Ls[nc + j*4 + 1][kr] = f2bf(v.y);
            Ls[nc + j*4 + 2][kr] = f2bf(v.z);
            Ls[nc + j*4 + 3][kr] = f2bf(v.w);
        }
    }
    __syncthreads();
    {
        int nr = t >> 2, kc = (t & 3) * 16;
        u16x8 o0 = *(const u16x8*)&Ls[nr][kc];
        u16x8 o1 = *(const u16x8*)&Ls[nr][kc + 8];
        *(u16x8*)(Wt + (size_t)(n0 + nr) * KDIM + k0 + kc)     = o0;
        *(u16x8*)(Wt + (size_t)(n0 + nr) * KDIM + k0 + kc + 8) = o1;
    }
}

// ---------------------------------------------------------------------------
// GEMM: C[4096, NC] = A[4096,1024]bf16 @ Wt[NC,1024]bf16^T + bias
// m97 structure: 128x128 tile, 4 waves, BK=64, global_load_lds w16 staging
// with pre-swizzled source + XOR-swizzled ds_read (both-sides involution).
// ---------------------------------------------------------------------------
template<int NC, int EPI>
__global__ __launch_bounds__(256) void gemm_k(
    const unsigned short* __restrict__ A, const unsigned short* __restrict__ Wt,
    const float* __restrict__ bias, float* __restrict__ Of,
    unsigned short* __restrict__ Qb, unsigned short* __restrict__ Kb,
    unsigned short* __restrict__ Vt)
{
    __shared__ unsigned short As[128 * 64];   // swizzled content, linear layout
    __shared__ unsigned short Bs[128 * 64];

    const int tid  = threadIdx.x;
    const int lane = tid & 63;
    const int wid  = tid >> 6;
    const int m0 = blockIdx.x * 128;
    const int n0 = blockIdx.y * 128;
    const int wm = (wid >> 1) * 64;
    const int wn = (wid & 1) * 64;
    const int rl = lane & 15;

    // staging geometry: wave stages rows wid*32 + 8c + (lane>>3); slot = lane&7
    const int r8 = lane >> 3, s8 = lane & 7;
    const int swzs = (s8 ^ r8) * 8;           // pre-swizzled source elem offset

    f32x4 acc[4][4] = {};

    for (int k0 = 0; k0 < KDIM; k0 += 64) {
        #pragma unroll
        for (int c = 0; c < 4; c++) {
            int row = (wid << 5) + (c << 3) + r8;
            gld16(A  + (size_t)(m0 + row) * KDIM + k0 + swzs, &As[(size_t)((wid<<5)+(c<<3)) * 64]);
            gld16(Wt + (size_t)(n0 + row) * KDIM + k0 + swzs, &Bs[(size_t)((wid<<5)+(c<<3)) * 64]);
        }
        __syncthreads();   // drains vmcnt: tile ready
        #pragma unroll
        for (int kc = 0; kc < 2; kc++) {
            const int sb = kc * 4 + (lane >> 4);      // base slot of this k-chunk
            bf16x8 af[4], bfr[4];
            #pragma unroll
            for (int f = 0; f < 4; f++) {
                int sw = (sb ^ (rl & 7)) * 8;
                af[f]  = *(const bf16x8*)&As[(wm + f*16 + rl) * 64 + sw];
                bfr[f] = *(const bf16x8*)&Bs[(wn + f*16 + rl) * 64 + sw];
            }
            __builtin_amdgcn_s_setprio(1);
            #pragma unroll
            for (int i = 0; i < 4; i++)
                #pragma unroll
                for (int j = 0; j < 4; j++)
                    acc[i][j] = __builtin_amdgcn_mfma_f32_16x16x32_bf16(af[i], bfr[j], acc[i][j], 0, 0, 0);
            __builtin_amdgcn_s_setprio(0);
        }
        __syncthreads();
    }

    #pragma unroll
    for (int j = 0; j < 4; j++) {
        int gn = n0 + wn + j*16 + rl;
        float bv = bias[gn];
        #pragma unroll
        for (int i = 0; i < 4; i++) {
            int gm0 = m0 + wm + i*16 + (lane >> 4) * 4;
            #pragma unroll
            for (int r = 0; r < 4; r++) {
                float v = acc[i][j][r] + bv;
                int gm = gm0 + r;
                if (EPI == 0) {
                    int which = gn >> 10;          // 0=q 1=k 2=v
                    int cw = gn & 1023;
                    int h = cw >> 6, d = cw & 63;
                    int b = gm >> 11, t = gm & 2047;
                    size_t bh = (size_t)(b * NHEAD + h);
                    if (which == 0)      Qb[(bh * T_SEQ + t) * HDIM + d] = f2bf(v * SCALE_L2E);
                    else if (which == 1) Kb[(bh * T_SEQ + t) * HDIM + d] = f2bf(v);
                    else                 Vt[(bh * HDIM + d) * T_SEQ + t] = f2bf(v);
                } else {
                    Of[(size_t)gm * NC + gn] = v;
                }
            }
        }
    }
}

// ---------------------------------------------------------------------------
// Causal flash attention. 4 waves = 128 q-rows per block; 16 q-tiles,
// heavy-first on slow grid axis (LPT balance, ~2 blocks/CU). KVBLK=64,
// triple-buffered global_load_lds (counted vmcnt(8), raw barriers),
// XOR-swizzled K/V LDS. Swapped-QK^T 32x32, lane-local exp2 softmax,
// defer-max, cvt_pk+permlane P packing.
// ---------------------------------------------------------------------------
__global__ __launch_bounds__(256) void attn_k(
    const unsigned short* __restrict__ Qb, const unsigned short* __restrict__ Kb,
    const unsigned short* __restrict__ Vt, unsigned short* __restrict__ AO)
{
    // tile buffer: K[64 rows][64 el swz] 8KB + V[64 d-rows][64 el swz] 8KB
    __shared__ unsigned short sbuf[3 * 8192];

    const int tid  = threadIdx.x;
    const int lane = tid & 63;
    const int w    = tid >> 6;                  // 0..3
    const int bh   = blockIdx.x;                // 0..31
    const int qt   = 15 - blockIdx.y;           // heavy q-tiles dispatched first
    const int q0w  = qt * 128 + w * 32;
    const int ql   = lane & 31;
    const int hi   = lane >> 5;
    const int qg   = q0w + ql;
    const int nt   = 2 * qt + 2;                // 64-kv tiles

    const unsigned short* Qp = Qb + (size_t)bh * T_SEQ * HDIM;
    const unsigned short* Kp = Kb + (size_t)bh * T_SEQ * HDIM;
    const unsigned short* Vp = Vt + (size_t)bh * HDIM * T_SEQ;

    // staging role: waves 0,1 stage K rows w*32+8c+r8; waves 2,3 stage V d-rows
    const int r8 = lane >> 3, s8 = lane & 7;
    const int swzs = (s8 ^ r8) * 8;
    const unsigned short* sp0;                  // chunk-0 source (tile 0)
    size_t stepE, cstep;                        // per-tile / per-chunk source advance
    int dstbase;                                // elem offset of wave slice in buffer
    if (w < 2) {
        sp0 = Kp + (size_t)((w << 5) + r8) * HDIM + swzs;
        stepE = 64 * HDIM; cstep = 8 * HDIM;
        dstbase = (w << 5) * 64;
    } else {
        sp0 = Vp + (size_t)(((w - 2) << 5) + r8) * T_SEQ + swzs;
        stepE = 64; cstep = 8 * T_SEQ;
        dstbase = 4096 + (((w - 2) << 5)) * 64;
    }

    // Q fragments (held all kernel); drain before staging so vmcnt stays uniform
    bf16x8 qf[4];
    #pragma unroll
    for (int dc = 0; dc < 4; dc++)
        qf[dc] = *(const bf16x8*)(Qp + (size_t)qg * HDIM + dc*16 + hi*8);
    asm volatile("s_waitcnt vmcnt(0)" ::: "memory");

    float m_run = -INFINITY, l_run = 0.f;
    f32x16 o0 = {}, o1 = {};

    // prologue: stage tiles 0,1,2 (4 gld16 each)
    #pragma unroll
    for (int pt = 0; pt < 3; pt++) {
        int ct = pt < nt ? pt : nt - 1;
        #pragma unroll
        for (int c = 0; c < 4; c++)
            gld16(sp0 + (size_t)ct * stepE + c * cstep,
                  &sbuf[pt * 8192 + dstbase + c * 512]);
    }

    int bsel = 0;
    for (int t = 0; t < nt; ++t) {
        const int c0 = t << 6;
        asm volatile("s_waitcnt vmcnt(8)" ::: "memory");   // tile t landed
        __builtin_amdgcn_s_barrier();
        __builtin_amdgcn_sched_barrier(0);

        if (c0 <= q0w) {
            const char* kb = (const char*)&sbuf[bsel * 8192];
            const char* vb = kb + 8192;
            const bool a1 = (c0 + 32 <= q0w);

            // ---- S^T = K·(Q*scale)^T for chunk0 (+chunk1 if active) ----
            f32x16 s0 = {}, s1 = {};
            __builtin_amdgcn_s_setprio(1);
            #pragma unroll
            for (int dc = 0; dc < 4; dc++) {
                int sw = (((dc << 1) | hi) ^ (ql & 7)) << 4;
                bf16x8 kf = *(const bf16x8*)(kb + ql*128 + sw);
                s0 = __builtin_amdgcn_mfma_f32_32x32x16_bf16(kf, qf[dc], s0, 0, 0, 0);
            }
            if (a1) {
                #pragma unroll
                for (int dc = 0; dc < 4; dc++) {
                    int sw = (((dc << 1) | hi) ^ (ql & 7)) << 4;
                    bf16x8 kf = *(const bf16x8*)(kb + 4096 + ql*128 + sw);
                    s1 = __builtin_amdgcn_mfma_f32_32x32x16_bf16(kf, qf[dc], s1, 0, 0, 0);
                }
            }
            __builtin_amdgcn_s_setprio(0);

            // ---- masks (diagonal chunks only; wave-uniform branches) ----
            float pm0[16], pm1[16];
            #pragma unroll
            for (int r = 0; r < 16; r++) { pm0[r] = s0[r]; pm1[r] = s1[r]; }
            if (c0 == q0w) {
                #pragma unroll
                for (int r = 0; r < 16; r++) {
                    int kv = c0 + (r & 3) + 8 * (r >> 2) + 4 * hi;
                    pm0[r] = (kv > qg) ? -INFINITY : pm0[r];
                }
            }
            if (a1 && (c0 + 32 == q0w)) {
                #pragma unroll
                for (int r = 0; r < 16; r++) {
                    int kv = c0 + 32 + (r & 3) + 8 * (r >> 2) + 4 * hi;
                    pm1[r] = (kv > qg) ? -INFINITY : pm1[r];
                }
            }

            // ---- combined online softmax over the 64-kv tile ----
            float tm = pm0[0];
            #pragma unroll
            for (int r = 1; r < 16; r++) tm = fmaxf(tm, pm0[r]);
            if (a1) {
                #pragma unroll
                for (int r = 0; r < 16; r++) tm = fmaxf(tm, pm1[r]);
            }
            tm = fmaxf(tm, __shfl_xor(tm, 32));
            if (__any(tm > m_run + 11.5f)) {       // defer-max (T13)
                float mn = fmaxf(m_run, tm);
                float sf = exp2f(m_run - mn);
                m_run = mn;
                l_run *= sf;
                #pragma unroll
                for (int r = 0; r < 16; r++) { o0[r] *= sf; o1[r] *= sf; }
            }
            float p0[16], p1[16]; float rs = 0.f;
            #pragma unroll
            for (int r = 0; r < 16; r++) { p0[r] = exp2f(pm0[r] - m_run); rs += p0[r]; }
            if (a1) {
                #pragma unroll
                for (int r = 0; r < 16; r++) { p1[r] = exp2f(pm1[r] - m_run); rs += p1[r]; }
            }
            rs += __shfl_xor(rs, 32);
            l_run += rs;

            // ---- V frags (swizzled LDS) ----
            const int swv0 = ((0 + hi) ^ (ql & 7)) << 4;   // chunk0 kv grp 0
            const int swv1 = ((2 + hi) ^ (ql & 7)) << 4;   // chunk0 kv grp 1
            const int swv2 = ((4 + hi) ^ (ql & 7)) << 4;   // chunk1 kv grp 0
            const int swv3 = ((6 + hi) ^ (ql & 7)) << 4;   // chunk1 kv grp 1
            const char* vrow0 = vb + ql * 128;
            const char* vrow1 = vb + (32 + ql) * 128;

            // ---- pack P chunk0: 8 cvt_pk + 4 permlane32_swap ----
            unsigned int c[8];
            #pragma unroll
            for (int i = 0; i < 8; i++) c[i] = cvt_pk_bf16(p0[2*i], p0[2*i+1]);
            pl32swap(c[0], c[2]);  pl32swap(c[1], c[3]);
            pl32swap(c[4], c[6]);  pl32swap(c[5], c[7]);
            u32x4 b0 = {c[0], c[1], c[2], c[3]};
            u32x4 b1 = {c[4], c[5], c[6], c[7]};
            bf16x8 pf0 = __builtin_bit_cast(bf16x8, b0);
            bf16x8 pf1 = __builtin_bit_cast(bf16x8, b1);

            bf16x8 v00 = *(const bf16x8*)(vrow0 + swv0);
            bf16x8 v01 = *(const bf16x8*)(vrow0 + swv1);
            bf16x8 v10 = *(const bf16x8*)(vrow1 + swv0);
            bf16x8 v11 = *(const bf16x8*)(vrow1 + swv1);
            __builtin_amdgcn_s_setprio(1);
            o0 = __builtin_amdgcn_mfma_f32_32x32x16_bf16(v00, pf0, o0, 0, 0, 0);
            o0 = __builtin_amdgcn_mfma_f32_32x32x16_bf16(v01, pf1, o0, 0, 0, 0);
            o1 = __builtin_amdgcn_mfma_f32_32x32x16_bf16(v10, pf0, o1, 0, 0, 0);
            o1 = __builtin_amdgcn_mfma_f32_32x32x16_bf16(v11, pf1, o1, 0, 0, 0);
            __builtin_amdgcn_s_setprio(0);

            if (a1) {
                #pragma unroll
                for (int i = 0; i < 8; i++) c[i] = cvt_pk_bf16(p1[2*i], p1[2*i+1]);
                pl32swap(c[0], c[2]);  pl32swap(c[1], c[3]);
                pl32swap(c[4], c[6]);  pl32swap(c[5], c[7]);
                u32x4 b2 = {c[0], c[1], c[2], c[3]};
                u32x4 b3 = {c[4], c[5], c[6], c[7]};
                bf16x8 pf2 = __builtin_bit_cast(bf16x8, b2);
                bf16x8 pf3 = __builtin_bit_cast(bf16x8, b3);
                bf16x8 v02 = *(const bf16x8*)(vrow0 + swv2);
                bf16x8 v03 = *(const bf16x8*)(vrow0 + swv3);
                bf16x8 v12 = *(const bf16x8*)(vrow1 + swv2);
                bf16x8 v13 = *(const bf16x8*)(vrow1 + swv3);
                __builtin_amdgcn_s_setprio(1);
                o0 = __builtin_amdgcn_mfma_f32_32x32x16_bf16(v02, pf2, o0, 0, 0, 0);
                o0 = __builtin_amdgcn_mfma_f32_32x32x16_bf16(v03, pf3, o0, 0, 0, 0);
                o1 = __builtin_amdgcn_mfma_f32_32x32x16_bf16(v12, pf2, o1, 0, 0, 0);
                o1 = __builtin_amdgcn_mfma_f32_32x32x16_bf16(v13, pf3, o1, 0, 0, 0);
                __builtin_amdgcn_s_setprio(0);
            }
        }

        __builtin_amdgcn_sched_barrier(0);
        __builtin_amdgcn_s_barrier();              // all done reading buf[bsel]
        int ct = t + 3; if (ct > nt - 1) ct = nt - 1;   // dummy keeps vmcnt uniform
        #pragma unroll
        for (int cch = 0; cch < 4; cch++)
            gld16(sp0 + (size_t)ct * stepE + cch * cstep,
                  &sbuf[bsel * 8192 + dstbase + cch * 512]);
        if (++bsel == 3) bsel = 0;
    }

    // ---- epilogue: O^T[d][q] -> AO[b, t=qg, h*64+d], packed 8B stores ----
    const float inv_l = 1.f / l_run;
    const int b = bh >> 4, h = bh & 15;
    unsigned short* aop = AO + ((size_t)(b * T_SEQ + qg)) * CDIM + h * HDIM;
    #pragma unroll
    for (int qd = 0; qd < 4; qd++) {
        uint2 w0, w1;
        w0.x = cvt_pk_bf16(o0[4*qd+0] * inv_l, o0[4*qd+1] * inv_l);
        w0.y = cvt_pk_bf16(o0[4*qd+2] * inv_l, o0[4*qd+3] * inv_l);
        w1.x = cvt_pk_bf16(o1[4*qd+0] * inv_l, o1[4*qd+1] * inv_l);
        w1.y = cvt_pk_bf16(o1[4*qd+2] * inv_l, o1[4*qd+3] * inv_l);
        *(uint2*)(aop + qd*8 + hi*4)      = w0;
        *(uint2*)(aop + 32 + qd*8 + hi*4) = w1;
    }
}

// ---------------------------------------------------------------------------
extern "C" void kernel_launch(void* const* d_in, const int* in_sizes, int n_in,
                              void* d_out, int out_size, void* d_ws, size_t ws_size,
                              hipStream_t stream) {
    const float* x      = (const float*)d_in[0];
    const float* w_qkv  = (const float*)d_in[1];
    const float* b_qkv  = (const float*)d_in[2];
    const float* w_proj = (const float*)d_in[3];
    const float* b_proj = (const float*)d_in[4];
    float* out = (float*)d_out;

    const size_t MI = (size_t)1 << 20;
    unsigned short* base = (unsigned short*)d_ws;
    unsigned short* Qb  = base;
    unsigned short* Kb  = base + 4*MI;
    unsigned short* Vt  = base + 8*MI;
    unsigned short* Wqt = base + 12*MI;
    unsigned short* Wpt = base + 15*MI;
    unsigned short* Xb  = base + 16*MI;
    unsigned short* AO  = Xb;   // Xb dead after QKV gemm

    prep_x<<<dim3(2048), 256, 0, stream>>>(x, Xb);
    prep_w<3072><<<dim3(48, 16), 256, 0, stream>>>(w_qkv, Wqt);
    prep_w<1024><<<dim3(16, 16), 256, 0, stream>>>(w_proj, Wpt);
    gemm_k<3072, 0><<<dim3(32, 24), 256, 0, stream>>>(
        Xb, Wqt, b_qkv, nullptr, Qb, Kb, Vt);
    attn_k<<<dim3(32, 16), 256, 0, stream>>>(Qb, Kb, Vt, AO);
    gemm_k<1024, 1><<<dim3(32, 8), 256, 0, stream>>>(
        AO, Wpt, b_proj, out, nullptr, nullptr, nullptr);
}